// Round 5
// baseline (171.786 us; speedup 1.0000x reference)
//
#include <hip/hip_runtime.h>

#define D 4096

typedef float fx4 __attribute__((ext_vector_type(4)));
typedef int   ix4 __attribute__((ext_vector_type(4)));

// ws layout (floats):
//   CS0 = 0      colsum0 [D]  (atomics; memset first)
//   CS1 = D      colsum1 [D]  (atomics; memset first)
//   RS1 = 2D     rowsum1 [D]
//   RS2 = 3D     rowsum2 [D]
//   MSG = 4D     m0,m1,m2,m3 [4][D]
#define CS0 0
#define CS1 D
#define RS1 (2 * D)
#define RS2 (3 * D)
#define MSG (4 * D)

// ---------------- pass 1: all reductions, one launch, 192 MB read ----------------
// 1536 blocks x 256 threads, uniform 256 KB/block:
//   [0,256)    t0 colsum: 64-row x 1024-col-quarter stripe, atomicAdd per column
//   [256,512)  t1 FUSED: 16 rows x full width; rowsum direct + colsum atomics
//   [512,1536) t2 rowsum: 4 rows/block, wave per row
__global__ void __launch_bounds__(256) reduce_all_kernel(
        const float* __restrict__ t0, const float* __restrict__ t1,
        const float* __restrict__ t2, float* __restrict__ ws) {
    int b = blockIdx.x;
    int tid = threadIdx.x;
    if (b < 256) {
        // ---- colsum of t0 (R3-proven) ----
        int q = b & 3, s = b >> 2;
        int c4 = q * 256 + tid;                    // fx4-column 0..1023
        int r0 = s * 64;
        const fx4* A4 = (const fx4*)t0;
        fx4 acc = (fx4){0.f, 0.f, 0.f, 0.f};
        #pragma unroll 8
        for (int r = 0; r < 64; ++r)
            acc += A4[(size_t)(r0 + r) * (D / 4) + c4];
        atomicAdd(&ws[CS0 + c4 * 4 + 0], acc.x);
        atomicAdd(&ws[CS0 + c4 * 4 + 1], acc.y);
        atomicAdd(&ws[CS0 + c4 * 4 + 2], acc.z);
        atomicAdd(&ws[CS0 + c4 * 4 + 3], acc.w);
    } else if (b < 512) {
        // ---- fused t1: 16 rows, rowsum + colsum in one read ----
        int s = b - 256;                           // stripe 0..255
        int r0 = s * 16;
        const fx4* A4 = (const fx4*)t1;
        fx4 ca0 = (fx4){0.f,0.f,0.f,0.f}, ca1 = ca0, ca2 = ca0, ca3 = ca0;
        float rp[16];
        #pragma unroll
        for (int r = 0; r < 16; ++r) {
            const fx4* R = A4 + (size_t)(r0 + r) * (D / 4);
            fx4 v0 = R[tid];
            fx4 v1 = R[tid + 256];
            fx4 v2 = R[tid + 512];
            fx4 v3 = R[tid + 768];
            ca0 += v0; ca1 += v1; ca2 += v2; ca3 += v3;
            fx4 t = (v0 + v1) + (v2 + v3);
            rp[r] = (t.x + t.y) + (t.z + t.w);
        }
        // rowsums: LDS transpose, one wave per 4 rows
        __shared__ float rbuf[16][256];
        #pragma unroll
        for (int r = 0; r < 16; ++r) rbuf[r][tid] = rp[r];
        __syncthreads();
        int wid = tid >> 6, lane = tid & 63;
        #pragma unroll
        for (int k = 0; k < 4; ++k) {
            int r = wid * 4 + k;
            float sres = (rbuf[r][lane] + rbuf[r][lane + 64]) +
                         (rbuf[r][lane + 128] + rbuf[r][lane + 192]);
            #pragma unroll
            for (int o = 32; o > 0; o >>= 1) sres += __shfl_down(sres, o);
            if (lane == 0) ws[RS1 + r0 + r] = sres;
        }
        // colsum atomics (4096 per block, same budget as t0 path)
        atomicAdd(&ws[CS1 + (tid        ) * 4 + 0], ca0.x);
        atomicAdd(&ws[CS1 + (tid        ) * 4 + 1], ca0.y);
        atomicAdd(&ws[CS1 + (tid        ) * 4 + 2], ca0.z);
        atomicAdd(&ws[CS1 + (tid        ) * 4 + 3], ca0.w);
        atomicAdd(&ws[CS1 + (tid +  256 ) * 4 + 0], ca1.x);
        atomicAdd(&ws[CS1 + (tid +  256 ) * 4 + 1], ca1.y);
        atomicAdd(&ws[CS1 + (tid +  256 ) * 4 + 2], ca1.z);
        atomicAdd(&ws[CS1 + (tid +  256 ) * 4 + 3], ca1.w);
        atomicAdd(&ws[CS1 + (tid +  512 ) * 4 + 0], ca2.x);
        atomicAdd(&ws[CS1 + (tid +  512 ) * 4 + 1], ca2.y);
        atomicAdd(&ws[CS1 + (tid +  512 ) * 4 + 2], ca2.z);
        atomicAdd(&ws[CS1 + (tid +  512 ) * 4 + 3], ca2.w);
        atomicAdd(&ws[CS1 + (tid +  768 ) * 4 + 0], ca3.x);
        atomicAdd(&ws[CS1 + (tid +  768 ) * 4 + 1], ca3.y);
        atomicAdd(&ws[CS1 + (tid +  768 ) * 4 + 2], ca3.z);
        atomicAdd(&ws[CS1 + (tid +  768 ) * 4 + 3], ca3.w);
    } else {
        // ---- rowsum of t2: wave per row (R3-proven) ----
        int lb = b - 512;                          // 0..1023
        int wid = tid >> 6, lane = tid & 63;
        int row = lb * 4 + wid;
        const fx4* R = (const fx4*)(t2 + (size_t)row * D);
        float ssum = 0.f;
        #pragma unroll
        for (int j = 0; j < 16; ++j) {
            fx4 v = R[lane + 64 * j];
            ssum += (v.x + v.y) + (v.z + v.w);
        }
        #pragma unroll
        for (int o = 32; o > 0; o >>= 1) ssum += __shfl_down(ssum, o);
        if (lane == 0) ws[RS2 + row] = ssum;
    }
}

// ---------------- pass 2: message chain (single block of 1024) ----------------

__device__ __forceinline__ float block_sum_1024(float v, float* red) {
    #pragma unroll
    for (int o = 32; o > 0; o >>= 1) v += __shfl_down(v, o);
    int lane = threadIdx.x & 63, wid = threadIdx.x >> 6;
    if (lane == 0) red[wid] = v;
    __syncthreads();
    if (threadIdx.x == 0) {
        float t = 0.f;
        #pragma unroll
        for (int w = 0; w < 16; ++w) t += red[w];
        red[0] = t;
    }
    __syncthreads();
    float r = red[0];
    __syncthreads();
    return r;
}

__global__ void __launch_bounds__(1024) messages_kernel(
        const float* __restrict__ ws,
        const int* __restrict__ op0, const int* __restrict__ op1,
        const int* __restrict__ op2, const int* __restrict__ op3,
        float* __restrict__ ws_w) {
    __shared__ float m0[D], m1[D], m2[D], m3[D];
    __shared__ float red[16];
    int tid = threadIdx.x;

    // vectorized op loads: thread t covers elements i = 4t..4t+3
    ix4 s0 = ((const ix4*)op0)[tid], d0 = ((const ix4*)op0)[1024 + tid];
    ix4 s1 = ((const ix4*)op1)[tid], d1 = ((const ix4*)op1)[1024 + tid];
    ix4 s2 = ((const ix4*)op2)[tid], d2 = ((const ix4*)op2)[1024 + tid];
    ix4 s3 = ((const ix4*)op3)[tid], d3 = ((const ix4*)op3)[1024 + tid];

    // prefetch gathers (all independent of the message chain)
    float g0[4], g1[4], g2[4], g3[4];
    #pragma unroll
    for (int k = 0; k < 4; ++k) {
        g0[k] = ws[CS0 + s0[k]];
        g1[k] = ws[CS1 + s1[k]];
        g2[k] = ws[RS2 + s2[k]];
        g3[k] = ws[RS1 + s3[k]];
    }

    fx4 z = (fx4){0.f, 0.f, 0.f, 0.f};
    ((fx4*)m0)[tid] = z; ((fx4*)m1)[tid] = z;
    ((fx4*)m2)[tid] = z; ((fx4*)m3)[tid] = z;
    __syncthreads();

    // m0 = remap(colsum0, op0)
    #pragma unroll
    for (int k = 0; k < 4; ++k) atomicAdd(&m0[d0[k]], g0[k]);
    __syncthreads();

    // S0 = sum(m0)
    fx4 pv = ((fx4*)m0)[tid];
    float S0 = block_sum_1024((pv.x + pv.y) + (pv.z + pv.w), red);

    // m1 = remap(colsum1 + S0, op1)
    #pragma unroll
    for (int k = 0; k < 4; ++k) atomicAdd(&m1[d1[k]], g1[k] + S0);
    __syncthreads();

    // m2 = remap(rowsum2 + 4095*m1, op2)
    #pragma unroll
    for (int k = 0; k < 4; ++k)
        atomicAdd(&m2[d2[k]], g2[k] + 4095.0f * m1[s2[k]]);
    __syncthreads();

    // S2 = sum(m2)
    pv = ((fx4*)m2)[tid];
    float S2 = block_sum_1024((pv.x + pv.y) + (pv.z + pv.w), red);

    // m3 = remap(rowsum1 + 4095*m0 + S2, op3)
    #pragma unroll
    for (int k = 0; k < 4; ++k)
        atomicAdd(&m3[d3[k]], g3[k] + 4095.0f * m0[s3[k]] + S2);
    __syncthreads();

    // export (vectorized)
    ((fx4*)(ws_w + MSG + 0 * D))[tid] = ((fx4*)m0)[tid];
    ((fx4*)(ws_w + MSG + 1 * D))[tid] = ((fx4*)m1)[tid];
    ((fx4*)(ws_w + MSG + 2 * D))[tid] = ((fx4*)m2)[tid];
    ((fx4*)(ws_w + MSG + 3 * D))[tid] = ((fx4*)m3)[tid];
}

// ---------------- pass 3: apply broadcasts ----------------
// 3*D blocks x 256; block b: row (b & 4095) of matrix (b >> 12).
__global__ void __launch_bounds__(256) apply_kernel(
        const float* __restrict__ t0, const float* __restrict__ t1,
        const float* __restrict__ t2, const float* __restrict__ msgs,
        float* __restrict__ out) {
    int b = blockIdx.x;
    int mat = b >> 12;
    int row = b & (D - 1);
    const float* m0 = msgs + 0 * D;
    const float* m1 = msgs + 1 * D;
    const float* m2 = msgs + 2 * D;
    const float* m3 = msgs + 3 * D;
    size_t base = (size_t)row * D;
    fx4* dst = (fx4*)(out + (size_t)mat * D * D + base);

    if (mat == 0) {
        const fx4* src = (const fx4*)(t0 + base);
        const fx4* c4 = (const fx4*)m3;
        for (int i = threadIdx.x; i < D / 4; i += 256) {
            fx4 r = __builtin_nontemporal_load(&src[i]) + c4[i];
            __builtin_nontemporal_store(r, &dst[i]);
        }
    } else if (mat == 1) {
        const fx4* src = (const fx4*)(t1 + base);
        const fx4* c4 = (const fx4*)m2;
        float rr = m0[row];
        for (int i = threadIdx.x; i < D / 4; i += 256) {
            fx4 r = __builtin_nontemporal_load(&src[i]) + c4[i] + rr;
            __builtin_nontemporal_store(r, &dst[i]);
        }
    } else {
        const fx4* src = (const fx4*)(t2 + base);
        float rr = m1[row];
        for (int i = threadIdx.x; i < D / 4; i += 256) {
            fx4 r = __builtin_nontemporal_load(&src[i]) + rr;
            __builtin_nontemporal_store(r, &dst[i]);
        }
    }
}

extern "C" void kernel_launch(void* const* d_in, const int* in_sizes, int n_in,
                              void* d_out, int out_size, void* d_ws, size_t ws_size,
                              hipStream_t stream) {
    const float* t0 = (const float*)d_in[0];
    const float* t1 = (const float*)d_in[1];
    const float* t2 = (const float*)d_in[2];
    const int* op0 = (const int*)d_in[3];
    const int* op1 = (const int*)d_in[4];
    const int* op2 = (const int*)d_in[5];
    const int* op3 = (const int*)d_in[6];
    float* out = (float*)d_out;
    float* ws = (float*)d_ws;

    // zero the atomic targets: colsum0, colsum1
    hipMemsetAsync(ws, 0, 2 * D * sizeof(float), stream);

    reduce_all_kernel<<<1536, 256, 0, stream>>>(t0, t1, t2, ws);
    messages_kernel<<<1, 1024, 0, stream>>>(ws, op0, op1, op2, op3, ws);
    apply_kernel<<<3 * D, 256, 0, stream>>>(t0, t1, t2, ws + MSG, out);
}

// Round 6
// 149.449 us; speedup vs baseline: 1.1495x; 1.1495x over previous
//
#include <hip/hip_runtime.h>

#define D 4096

typedef float fx4 __attribute__((ext_vector_type(4)));

// ws layout (floats):
//   CS0 = 0      colsum0 [D]  (atomics; memset first)
//   CS1 = D      colsum1 [D]  (atomics; memset first)
//   RS1 = 2D     rowsum1 [D]
//   RS2 = 3D     rowsum2 [D]
//   MSG = 4D     m0,m1,m2,m3 [4][D]
#define CS0 0
#define CS1 D
#define RS1 (2 * D)
#define RS2 (3 * D)
#define MSG (4 * D)

// ---------------- pass 1: reductions (R3-proven structure) ----------------
// 2560 blocks x 256:
//   [0,256)     colsum t0 -> atomics CS0
//   [256,512)   colsum t1 -> atomics CS1
//   [512,1536)  rowsum t1 -> RS1   (concurrent with colsum t1: 2nd read IC-hits)
//   [1536,2560) rowsum t2 -> RS2   (read LAST -> freshest in IC for apply)
__global__ void __launch_bounds__(256) reduce_all_kernel(
        const float* __restrict__ t0, const float* __restrict__ t1,
        const float* __restrict__ t2, float* __restrict__ ws) {
    int b = blockIdx.x;
    if (b < 512) {
        const float* A = (b < 256) ? t0 : t1;
        float* out = ws + ((b < 256) ? CS0 : CS1);
        int lb = b & 255;
        int c4 = (lb & 3) * 256 + threadIdx.x;     // fx4-column 0..1023
        int r0 = (lb >> 2) * 64;                   // 64-row stripe
        const fx4* A4 = (const fx4*)A;
        fx4 s = (fx4){0.f, 0.f, 0.f, 0.f};
        #pragma unroll 8
        for (int r = 0; r < 64; ++r)
            s += A4[(size_t)(r0 + r) * (D / 4) + c4];
        atomicAdd(&out[c4 * 4 + 0], s.x);
        atomicAdd(&out[c4 * 4 + 1], s.y);
        atomicAdd(&out[c4 * 4 + 2], s.z);
        atomicAdd(&out[c4 * 4 + 3], s.w);
    } else {
        int lb = (b - 512) & 1023;                 // 0..1023
        const float* A = (b < 1536) ? t1 : t2;
        float* out = ws + ((b < 1536) ? RS1 : RS2);
        int wid = threadIdx.x >> 6, lane = threadIdx.x & 63;
        int row = lb * 4 + wid;
        const fx4* R = (const fx4*)(A + (size_t)row * D);
        float s = 0.f;
        #pragma unroll
        for (int j = 0; j < 16; ++j) {
            fx4 v = R[lane + 64 * j];
            s += (v.x + v.y) + (v.z + v.w);
        }
        #pragma unroll
        for (int o = 32; o > 0; o >>= 1) s += __shfl_down(s, o);
        if (lane == 0) out[row] = s;
    }
}

// ---------------- pass 2: message chain (single block, R3-proven) ----------------

__device__ __forceinline__ float block_sum_1024(float v, float* red) {
    #pragma unroll
    for (int o = 32; o > 0; o >>= 1) v += __shfl_down(v, o);
    int lane = threadIdx.x & 63, wid = threadIdx.x >> 6;
    if (lane == 0) red[wid] = v;
    __syncthreads();
    if (threadIdx.x == 0) {
        float t = 0.f;
        #pragma unroll
        for (int w = 0; w < 16; ++w) t += red[w];
        red[0] = t;
    }
    __syncthreads();
    float r = red[0];
    __syncthreads();
    return r;
}

__global__ void __launch_bounds__(1024) messages_kernel(
        const float* __restrict__ ws,
        const int* __restrict__ op0, const int* __restrict__ op1,
        const int* __restrict__ op2, const int* __restrict__ op3,
        float* __restrict__ ws_w) {
    __shared__ float m0[D], m1[D], m2[D], m3[D];
    __shared__ float red[16];
    int tid = threadIdx.x;

    int s0[4], d0[4], s1[4], d1[4], s2[4], d2[4], s3[4], d3[4];
    #pragma unroll
    for (int k = 0; k < 4; ++k) {
        int i = tid + k * 1024;
        s0[k] = op0[i]; d0[k] = op0[D + i];
        s1[k] = op1[i]; d1[k] = op1[D + i];
        s2[k] = op2[i]; d2[k] = op2[D + i];
        s3[k] = op3[i]; d3[k] = op3[D + i];
    }
    float g0[4], g1[4], g2[4], g3[4];
    #pragma unroll
    for (int k = 0; k < 4; ++k) {
        g0[k] = ws[CS0 + s0[k]];
        g1[k] = ws[CS1 + s1[k]];
        g2[k] = ws[RS2 + s2[k]];
        g3[k] = ws[RS1 + s3[k]];
    }

    #pragma unroll
    for (int k = 0; k < 4; ++k) {
        int i = tid + k * 1024;
        m0[i] = 0.f; m1[i] = 0.f; m2[i] = 0.f; m3[i] = 0.f;
    }
    __syncthreads();

    #pragma unroll
    for (int k = 0; k < 4; ++k) atomicAdd(&m0[d0[k]], g0[k]);
    __syncthreads();

    float p = 0.f;
    #pragma unroll
    for (int k = 0; k < 4; ++k) p += m0[tid + k * 1024];
    float S0 = block_sum_1024(p, red);

    #pragma unroll
    for (int k = 0; k < 4; ++k) atomicAdd(&m1[d1[k]], g1[k] + S0);
    __syncthreads();

    #pragma unroll
    for (int k = 0; k < 4; ++k)
        atomicAdd(&m2[d2[k]], g2[k] + 4095.0f * m1[s2[k]]);
    __syncthreads();

    p = 0.f;
    #pragma unroll
    for (int k = 0; k < 4; ++k) p += m2[tid + k * 1024];
    float S2 = block_sum_1024(p, red);

    #pragma unroll
    for (int k = 0; k < 4; ++k)
        atomicAdd(&m3[d3[k]], g3[k] + 4095.0f * m0[s3[k]] + S2);
    __syncthreads();

    #pragma unroll
    for (int k = 0; k < 4; ++k) {
        int i = tid + k * 1024;
        ws_w[MSG + 0 * D + i] = m0[i];
        ws_w[MSG + 1 * D + i] = m1[i];
        ws_w[MSG + 2 * D + i] = m2[i];
        ws_w[MSG + 3 * D + i] = m3[i];
    }
}

// ---------------- pass 3: apply broadcasts ----------------
// 3072 blocks x 256. Block b: mat = 2 - (b>>10) (t2 FIRST: freshest in IC),
// 4 rows per block; all 16 loads issued before stores (MLP); column-message
// row loaded once and reused across the 4 rows.
__global__ void __launch_bounds__(256) apply_kernel(
        const float* __restrict__ t0, const float* __restrict__ t1,
        const float* __restrict__ t2, const float* __restrict__ msgs,
        float* __restrict__ out) {
    int b = blockIdx.x;
    int mat = 2 - (b >> 10);
    int rblk = b & 1023;
    int tid = threadIdx.x;
    int row0 = rblk * 4;
    const float* m0 = msgs + 0 * D;
    const float* m1 = msgs + 1 * D;
    const float* m2 = msgs + 2 * D;
    const float* m3 = msgs + 3 * D;
    const float* src_m = (mat == 0) ? t0 : (mat == 1) ? t1 : t2;
    fx4* dst0 = (fx4*)(out + (size_t)mat * D * D + (size_t)row0 * D);
    const fx4* src0 = (const fx4*)(src_m + (size_t)row0 * D);

    fx4 v[4][4];
    #pragma unroll
    for (int r = 0; r < 4; ++r)
        #pragma unroll
        for (int k = 0; k < 4; ++k)
            v[r][k] = src0[(size_t)r * (D / 4) + tid + 256 * k];

    if (mat == 2) {
        #pragma unroll
        for (int r = 0; r < 4; ++r) {
            float rr = m1[row0 + r];
            #pragma unroll
            for (int k = 0; k < 4; ++k)
                __builtin_nontemporal_store(v[r][k] + rr,
                    &dst0[(size_t)r * (D / 4) + tid + 256 * k]);
        }
    } else if (mat == 1) {
        const fx4* c4 = (const fx4*)m2;
        fx4 c[4];
        #pragma unroll
        for (int k = 0; k < 4; ++k) c[k] = c4[tid + 256 * k];
        #pragma unroll
        for (int r = 0; r < 4; ++r) {
            float rr = m0[row0 + r];
            #pragma unroll
            for (int k = 0; k < 4; ++k)
                __builtin_nontemporal_store(v[r][k] + c[k] + rr,
                    &dst0[(size_t)r * (D / 4) + tid + 256 * k]);
        }
    } else {
        const fx4* c4 = (const fx4*)m3;
        fx4 c[4];
        #pragma unroll
        for (int k = 0; k < 4; ++k) c[k] = c4[tid + 256 * k];
        #pragma unroll
        for (int r = 0; r < 4; ++r) {
            #pragma unroll
            for (int k = 0; k < 4; ++k)
                __builtin_nontemporal_store(v[r][k] + c[k],
                    &dst0[(size_t)r * (D / 4) + tid + 256 * k]);
        }
    }
}

extern "C" void kernel_launch(void* const* d_in, const int* in_sizes, int n_in,
                              void* d_out, int out_size, void* d_ws, size_t ws_size,
                              hipStream_t stream) {
    const float* t0 = (const float*)d_in[0];
    const float* t1 = (const float*)d_in[1];
    const float* t2 = (const float*)d_in[2];
    const int* op0 = (const int*)d_in[3];
    const int* op1 = (const int*)d_in[4];
    const int* op2 = (const int*)d_in[5];
    const int* op3 = (const int*)d_in[6];
    float* out = (float*)d_out;
    float* ws = (float*)d_ws;

    hipMemsetAsync(ws, 0, 2 * D * sizeof(float), stream);

    reduce_all_kernel<<<2560, 256, 0, stream>>>(t0, t1, t2, ws);
    messages_kernel<<<1, 1024, 0, stream>>>(ws, op0, op1, op2, op3, ws);
    apply_kernel<<<3072, 256, 0, stream>>>(t0, t1, t2, ws + MSG, out);
}